// Round 11
// baseline (198.739 us; speedup 1.0000x reference)
//
#include <hip/hip_runtime.h>
#include <hip/hip_bf16.h>

#define B_ 4
#define S_ 4096
#define E_ 1024
#define D_ 128

typedef unsigned short u16;
typedef __bf16 bf16x8 __attribute__((ext_vector_type(8)));
typedef unsigned short u16x8 __attribute__((ext_vector_type(8)));
typedef float f32x4 __attribute__((ext_vector_type(4)));

__device__ inline u16 f2bf(float f) {
    __bf16 h = (__bf16)f;
    return __builtin_bit_cast(u16, h);
}

// direct global->LDS DMA, 16B per lane, no VGPR round-trip
__device__ inline void gload16(const void* g, void* l) {
    __builtin_amdgcn_global_load_lds(
        (const __attribute__((address_space(1))) void*)g,
        (__attribute__((address_space(3))) void*)l, 16, 0, 0);
}

// ---------------------------------------------------------------------------
// Kernel 0: W [E,D] f32 -> Wt [3][D][E] bf16 (proj 0 pre-scaled by 1/sqrt(D))
// ---------------------------------------------------------------------------
__global__ __launch_bounds__(256) void wt_kernel(const float* __restrict__ Wq,
                                                 const float* __restrict__ Wk,
                                                 const float* __restrict__ Wv,
                                                 u16* __restrict__ Wt) {
    int tid = blockIdx.x * 256 + threadIdx.x;       // 0 .. 3*131072-1
    int w = tid >> 17;                               // 131072 = 2^17
    int rem = tid & 131071;
    int d = rem >> 10;
    int e = rem & 1023;
    const float* W = (w == 0) ? Wq : ((w == 1) ? Wk : Wv);
    float v = W[e * D_ + d];
    if (w == 0) v *= 0.08838834764831845f;           // 1/sqrt(128)
    Wt[tid] = f2bf(v);
}

// ---------------------------------------------------------------------------
// Kernel 1: QKV LDS-staged GEMM (unchanged from r10; fell off the top-5).
// ---------------------------------------------------------------------------
__global__ __launch_bounds__(512, 4) void qkv_fused(const float* __restrict__ x,
                                                    const u16* __restrict__ Wt,
                                                    u16* __restrict__ q,
                                                    u16* __restrict__ k,
                                                    u16* __restrict__ vT) {
    const int mrow0 = blockIdx.x * 64;
    const int wv = threadIdx.x >> 6;   // 0..7
    const int l = threadIdx.x & 63;
    const int g = l >> 4;
    const int c = l & 15;
    const int wr = wv >> 2;            // 0..1 (32-row half)
    const int wc = wv & 3;             // 0..3 (96-col group)

    __shared__ __align__(16) char wlds[2][24 * 1024];   // 48 KB dbuf W-tile

    auto STAGE_W = [&](int buf, int kbase) {
#pragma unroll
        for (int ii = 0; ii < 3; ii++) {
            int ct = wv * 3 + ii;                  // 0..23
            int proj = ct >> 3;
            int dcol = (ct & 7) * 16;
            const u16* gp = Wt + ((size_t)(proj * 128 + dcol + c) * 1024 + kbase + g * 8);
            gload16(gp, wlds[buf] + ct * 1024);
        }
    };

    STAGE_W(0, 0);

    const float* xrow[2];
#pragma unroll
    for (int sub = 0; sub < 2; sub++)
        xrow[sub] = x + (size_t)(mrow0 + wr * 32 + sub * 16 + c) * E_ + g * 8;

    f32x4 acc[2][6] = {};
    __syncthreads();                 // buf0 staged (implicit vmcnt drain)

    int buf = 0;
    for (int ks = 0; ks < 32; ks++) {
        if (ks < 31) STAGE_W(buf ^ 1, (ks + 1) * 32);

        bf16x8 av[2];
#pragma unroll
        for (int sub = 0; sub < 2; sub++) {
            const float4 x0 = *(const float4*)(xrow[sub] + ks * 32);
            const float4 x1 = *(const float4*)(xrow[sub] + ks * 32 + 4);
            union { bf16x8 v; __bf16 e[8]; } a;
            a.e[0] = (__bf16)x0.x; a.e[1] = (__bf16)x0.y;
            a.e[2] = (__bf16)x0.z; a.e[3] = (__bf16)x0.w;
            a.e[4] = (__bf16)x1.x; a.e[5] = (__bf16)x1.y;
            a.e[6] = (__bf16)x1.z; a.e[7] = (__bf16)x1.w;
            av[sub] = a.v;
        }

#pragma unroll
        for (int ct = 0; ct < 6; ct++) {
            u16x8 braw = *(const u16x8*)(wlds[buf] + (wc * 6 + ct) * 1024 + l * 16);
            bf16x8 bw = __builtin_bit_cast(bf16x8, braw);
#pragma unroll
            for (int sub = 0; sub < 2; sub++)
                acc[sub][ct] = __builtin_amdgcn_mfma_f32_16x16x32_bf16(av[sub], bw, acc[sub][ct], 0, 0, 0);
        }

        __syncthreads();             // reads done + next-buf staging drained
        buf ^= 1;
    }

#pragma unroll
    for (int sub = 0; sub < 2; sub++) {
#pragma unroll
        for (int ct = 0; ct < 6; ct++) {
            int gc = (wc * 6 + ct) * 16;
            int proj = gc >> 7;
            int dcol = gc & 127;
            if (proj < 2) {
                u16* dst = proj ? k : q;
#pragma unroll
                for (int j = 0; j < 4; j++) {
                    int row = mrow0 + wr * 32 + sub * 16 + g * 4 + j;
                    dst[(size_t)row * D_ + dcol + c] = f2bf(acc[sub][ct][j]);
                }
            } else {
                int srow = mrow0 + wr * 32 + sub * 16 + g * 4;
                int b = srow >> 12;
                int s = srow & 4095;
                ushort4 pk;
                pk.x = f2bf(acc[sub][ct][0]);
                pk.y = f2bf(acc[sub][ct][1]);
                pk.z = f2bf(acc[sub][ct][2]);
                pk.w = f2bf(acc[sub][ct][3]);
                *(ushort4*)(vT + ((size_t)(b * D_ + dcol + c)) * S_ + s) = pk;
            }
        }
    }
}

// ---------------------------------------------------------------------------
// Kernel 2: flash attention, 4-way KV split for 4 waves/SIMD.
// 512 thr = 8 waves = 2 q-subtiles (32 q-rows/block) x 4 kv-groups (group
// grp does tiles t*4+grp, KVBLK=32). Grid 512 (2 blocks/CU), XCD-swizzled.
// waves/CU = 4 x kv_split = 16 (r10's 2-way split pinned it at 8).
// Single-buffered 16KB KV buf per group (64KB) + 4KB plds ~= 74KB -> 2
// blocks/CU. Stage->barrier->compute->barrier per round; exposed stage
// drain is covered by the co-resident block.
// K and V staged in FRAGMENT ORDER [frag][lane][16B]: ds_read_b128 at
// base+l*16 is linear (zero bank conflicts, no swizzle VALU); per-lane
// global source address realizes the layout.
// Defer-max (T13, THR=8) skips the alpha-rescale when no tile max grows.
// 4-way (m,l,o) merge epilogue through LDS.
// ---------------------------------------------------------------------------
__global__ __launch_bounds__(512, 4) void attn_kernel(const u16* __restrict__ q,
                                                      const u16* __restrict__ k,
                                                      const u16* __restrict__ vT,
                                                      float* __restrict__ out) {
    // bijective XCD-chunk swizzle (nwg=512, 8 XCDs, chunk=64)
    int bid = blockIdx.x;
    int sw = (bid & 7) * 64 + (bid >> 3);
    const int b = sw >> 7;           // batch 0..3
    const int qt = sw & 127;         // q-tile 0..127 (32 rows)
    const int wv = threadIdx.x >> 6; // 0..7
    const int grp = wv & 3;          // kv group: tiles t*4+grp
    const int wq = wv >> 2;          // q-subtile 0..1
    const int l = threadIdx.x & 63;
    const int g = l >> 4;
    const int c = l & 15;
    const int qrow0 = qt * 32 + wq * 16;   // within batch

    __shared__ __align__(16) char kv_lds[4 * 16384];   // per-group K 8KB | V 8KB
    __shared__ __align__(16) u16 plds[8][512];         // per-wave 1KB P buffer
    __shared__ float cmB[4][32], clB[4][32];
    char* base = kv_lds + grp * 16384;
    u16* pw = &plds[wv][0];

    const char* kbb = (const char*)(k + (size_t)b * S_ * D_);
    const char* vbb = (const char*)(vT + (size_t)b * D_ * S_);

    // Q fragments, hoisted (scaled already, via Wq)
    bf16x8 aq[4];
    const u16* qp = q + ((size_t)(b * S_ + qrow0 + c)) * D_ + g * 8;
#pragma unroll
    for (int ks = 0; ks < 4; ks++) aq[ks] = *(const bf16x8*)(qp + ks * 32);

    f32x4 o[8] = {};
    float m[4], ll[4];
#pragma unroll
    for (int j = 0; j < 4; j++) { m[j] = -1e30f; ll[j] = 0.0f; }

    // stage one 32-kv tile in fragment order; 8 instrs per wave (2 waves/group)
    auto STAGE = [&](int kvbase) {
#pragma unroll
        for (int ii = 0; ii < 4; ii++) {     // K frags: idx=(tt,ks)
            int idx = wq * 4 + ii;           // 0..7
            int tt = idx >> 2, ks = idx & 3;
            const char* gp = kbb + (size_t)(kvbase + tt * 16 + c) * 256 + ks * 64 + g * 16;
            gload16(gp, base + idx * 1024);
        }
#pragma unroll
        for (int ii = 0; ii < 4; ii++) {     // V frags: idx=ct
            int ct = wq * 4 + ii;            // 0..7
            const char* gp = vbb + (size_t)(ct * 16 + c) * 8192 + (size_t)kvbase * 2 + g * 16;
            gload16(gp, base + 8192 + ct * 1024);
        }
    };

    for (int t = 0; t < 32; t++) {
        const int kvbase = (t * 4 + grp) * 32;
        STAGE(kvbase);
        __syncthreads();                     // vmcnt drained: buf ready

        // ---- S = Q K^T : 2 tiles of 16 kv-cols, K-dim 128 ----
        f32x4 s[2] = {};
        __builtin_amdgcn_s_setprio(1);
#pragma unroll
        for (int tt = 0; tt < 2; tt++) {
#pragma unroll
            for (int ks = 0; ks < 4; ks++) {
                u16x8 kr = *(const u16x8*)(base + (tt * 4 + ks) * 1024 + l * 16);
                bf16x8 bk = __builtin_bit_cast(bf16x8, kr);
                s[tt] = __builtin_amdgcn_mfma_f32_16x16x32_bf16(aq[ks], bk, s[tt], 0, 0, 0);
            }
        }
        __builtin_amdgcn_s_setprio(0);

        // ---- online softmax with defer-max (THR=8) ----
        float tmj[4];
        bool need = false;
#pragma unroll
        for (int j = 0; j < 4; j++) {
            float tm = fmaxf(s[0][j], s[1][j]);
            tm = fmaxf(tm, __shfl_xor(tm, 1));
            tm = fmaxf(tm, __shfl_xor(tm, 2));
            tm = fmaxf(tm, __shfl_xor(tm, 4));
            tm = fmaxf(tm, __shfl_xor(tm, 8));
            tmj[j] = tm;
            need = need || (tm > m[j] + 8.0f);
        }
        if (__any(need)) {
#pragma unroll
            for (int j = 0; j < 4; j++) {
                float mn = fmaxf(m[j], tmj[j]);
                float alpha = exp2f((m[j] - mn) * 1.44269504f);
                ll[j] *= alpha;
#pragma unroll
                for (int ct = 0; ct < 8; ct++) o[ct][j] *= alpha;
                m[j] = mn;
            }
        }
        float pv[2][4];
#pragma unroll
        for (int j = 0; j < 4; j++) {
            float rs = 0.f;
#pragma unroll
            for (int tt = 0; tt < 2; tt++) {
                float p = exp2f((s[tt][j] - m[j]) * 1.44269504f);
                pv[tt][j] = p;
                rs += p;
            }
            rs += __shfl_xor(rs, 1);
            rs += __shfl_xor(rs, 2);
            rs += __shfl_xor(rs, 4);
            rs += __shfl_xor(rs, 8);
            ll[j] += rs;
        }

        // ---- P -> LDS (wave-private), (r&3) XOR-swizzle ----
#pragma unroll
        for (int tt = 0; tt < 2; tt++) {
#pragma unroll
            for (int j = 0; j < 4; j++) {
                int r = g * 4 + j;
                int cf = tt * 16 + c;
                int byte = r * 64 + ((cf * 2) ^ ((r & 3) << 4));
                *(u16*)((char*)pw + byte) = f2bf(pv[tt][j]);
            }
        }

        // ---- PV: O += P[16,32] * V[32,128] ----
        int pbyte = c * 64 + ((g * 16) ^ ((c & 3) << 4));
        u16x8 praw = *(const u16x8*)((char*)pw + pbyte);
        bf16x8 pa = __builtin_bit_cast(bf16x8, praw);
        __builtin_amdgcn_s_setprio(1);
#pragma unroll
        for (int ct = 0; ct < 8; ct++) {
            u16x8 vr = *(const u16x8*)(base + 8192 + ct * 1024 + l * 16);
            bf16x8 bv = __builtin_bit_cast(bf16x8, vr);
            o[ct] = __builtin_amdgcn_mfma_f32_16x16x32_bf16(pa, bv, o[ct], 0, 0, 0);
        }
        __builtin_amdgcn_s_setprio(0);

        __syncthreads();                     // all reads done before next stage
    }

    // ---- 4-way merge: grps 1..3 -> LDS, grp 0 merges and stores ----
    if (grp != 0) {
        float* co = (float*)kv_lds + (size_t)(grp - 1) * 4096;   // 16KB each
#pragma unroll
        for (int ct = 0; ct < 8; ct++) {
#pragma unroll
            for (int j = 0; j < 4; j++)
                co[(size_t)(wq * 16 + g * 4 + j) * 128 + ct * 16 + c] = o[ct][j];
        }
        if (c == 0) {
#pragma unroll
            for (int j = 0; j < 4; j++) {
                cmB[grp][wq * 16 + g * 4 + j] = m[j];
                clB[grp][wq * 16 + g * 4 + j] = ll[j];
            }
        }
    }
    __syncthreads();
    if (grp == 0) {
#pragma unroll
        for (int j = 0; j < 4; j++) {
            int r = wq * 16 + g * 4 + j;
            float M = m[j];
#pragma unroll
            for (int gi = 1; gi < 4; gi++) M = fmaxf(M, cmB[gi][r]);
            float e0 = exp2f((m[j] - M) * 1.44269504f);
            float L = ll[j] * e0;
            float eg[3];
#pragma unroll
            for (int gi = 1; gi < 4; gi++) {
                eg[gi - 1] = exp2f((cmB[gi][r] - M) * 1.44269504f);
                L += clB[gi][r] * eg[gi - 1];
            }
            float rL = 1.0f / L;
            float* op = out + ((size_t)(b * S_ + qt * 32 + r)) * D_;
#pragma unroll
            for (int ct = 0; ct < 8; ct++) {
                float a = o[ct][j] * e0;
#pragma unroll
                for (int gi = 1; gi < 4; gi++)
                    a += ((float*)kv_lds)[(size_t)(gi - 1) * 4096 + (size_t)r * 128 + ct * 16 + c] * eg[gi - 1];
                op[ct * 16 + c] = a * rL;
            }
        }
    }
}

extern "C" void kernel_launch(void* const* d_in, const int* in_sizes, int n_in,
                              void* d_out, int out_size, void* d_ws, size_t ws_size,
                              hipStream_t stream) {
    const float* x  = (const float*)d_in[0];
    const float* Wq = (const float*)d_in[1];
    const float* Wk = (const float*)d_in[2];
    const float* Wv = (const float*)d_in[3];
    float* out = (float*)d_out;   // reference output dtype is float32

    // workspace layout (bytes): q 4MB | k 4MB | vT 4MB | Wt 768KB
    u16* q  = (u16*)d_ws;
    u16* k  = q  + (size_t)B_ * S_ * D_;
    u16* vT = k  + (size_t)B_ * S_ * D_;
    u16* Wt = vT + (size_t)B_ * S_ * D_;

    wt_kernel<<<(3 * D_ * E_) / 256, 256, 0, stream>>>(Wq, Wk, Wv, Wt);
    qkv_fused<<<(B_ * S_) / 64, 512, 0, stream>>>(x, Wt, q, k, vT);
    attn_kernel<<<(B_ * S_) / 32, 512, 0, stream>>>(q, k, vT, out);
}